// Round 1
// baseline (588.458 us; speedup 1.0000x reference)
//
#include <hip/hip_runtime.h>
#include <math.h>

#define NNODES 6000
#define NEDGES 192000
#define DIN 512
#define HDIM 128
#define ALPHA 1.0f
#define EOS 1e-10f

static const size_t NN = (size_t)NNODES * (size_t)NNODES;

// ---------------------------------------------------------------------------
// Kernel 1: per-node scalar g[i] = dot(relu(feat[i] @ w_emb + b_emb), wv)
// where wv[h] = 0.5*(w_mlp[h] + w_mlp[H+h]).  8 nodes per block, 128 threads
// (thread = h index).  Feature rows staged in LDS (contiguous nodes).
// ---------------------------------------------------------------------------
__global__ __launch_bounds__(128) void embed_g_kernel(
    const float* __restrict__ feat, const float* __restrict__ w_emb,
    const float* __restrict__ b_emb, const float* __restrict__ w_mlp,
    float* __restrict__ g) {
  __shared__ float sf[8 * DIN];
  __shared__ float red[2][8];
  const int t = threadIdx.x;
  const int nb = blockIdx.x * 8;

  // stage 8 feature rows (contiguous: 4096 floats = 1024 float4)
  const float4* f4 = (const float4*)(feat + (size_t)nb * DIN);
  float4* s4 = (float4*)sf;
#pragma unroll
  for (int k = 0; k < 8; ++k) s4[k * 128 + t] = f4[k * 128 + t];
  __syncthreads();

  const int h = t;
  float acc[8];
  const float b = b_emb[h];
#pragma unroll
  for (int n = 0; n < 8; ++n) acc[n] = b;

#pragma unroll 4
  for (int d = 0; d < DIN; ++d) {
    const float w = w_emb[d * HDIM + h];  // coalesced across h
#pragma unroll
    for (int n = 0; n < 8; ++n) acc[n] += sf[n * DIN + d] * w;  // LDS broadcast
  }

  const float wv = 0.5f * (w_mlp[h] + w_mlp[HDIM + h]);
  const int lane = t & 63, wave = t >> 6;
#pragma unroll
  for (int n = 0; n < 8; ++n) {
    float v = fmaxf(acc[n], 0.0f) * wv;
    for (int off = 32; off > 0; off >>= 1) v += __shfl_down(v, off, 64);
    if (lane == 0) red[wave][n] = v;
  }
  __syncthreads();
  if (t < 8) g[nb + t] = red[0][t] + red[1][t];
}

// ---------------------------------------------------------------------------
// Pass A: per-edge gate weights + last-write-wins winner via atomicMax(e+1)
// into the adj_unnorm output region (zeroed beforehand).
// ---------------------------------------------------------------------------
__global__ __launch_bounds__(256) void edge_weights_kernel(
    const int* __restrict__ edges, const float* __restrict__ g,
    const float* __restrict__ noise, const float* __restrict__ b_mlp,
    float* __restrict__ w_lp, float* __restrict__ w_hp,
    int* __restrict__ winner) {
  const int e = blockIdx.x * blockDim.x + threadIdx.x;
  if (e >= NEDGES) return;
  const int u = edges[e];
  const int v = edges[NEDGES + e];
  const float raw = g[u] + g[v] + b_mlp[0];
  const float x = noise[e] + raw;          // TEMP == 1.0
  const float wl = 1.0f / (1.0f + expf(-x));
  const float wh = 1.0f - wl;
  w_lp[e] = wl;
  w_hp[e] = wh;
  atomicMax(&winner[(size_t)u * NNODES + v], e + 1);
}

// ---------------------------------------------------------------------------
// Pass B: deduplicated row sums (only winner edges contribute — matches
// numpy scatter-set-then-sum semantics).
// ---------------------------------------------------------------------------
__global__ __launch_bounds__(256) void edge_deg_kernel(
    const int* __restrict__ edges, const float* __restrict__ w_lp,
    const float* __restrict__ w_hp, const int* __restrict__ winner,
    float* __restrict__ deg_lp, float* __restrict__ deg_hp) {
  const int e = blockIdx.x * blockDim.x + threadIdx.x;
  if (e >= NEDGES) return;
  const int u = edges[e];
  const int v = edges[NEDGES + e];
  if (winner[(size_t)u * NNODES + v] != e + 1) return;
  atomicAdd(&deg_lp[u], w_lp[e]);
  atomicAdd(&deg_hp[u], w_hp[e]);
}

// ---------------------------------------------------------------------------
// Pass C: inverse sqrt degrees (+1 for eye) + default diagonal values.
// adj_lp[i,i] = inv_lp^2 (from the eye); adj_hp[i,i] = 1 (mask=0 default).
// Self-loop edges override both in pass D.
// ---------------------------------------------------------------------------
__global__ __launch_bounds__(256) void node_inv_kernel(
    const float* __restrict__ deg_lp, const float* __restrict__ deg_hp,
    float* __restrict__ inv_lp, float* __restrict__ inv_hp,
    float* __restrict__ adj_lp, float* __restrict__ adj_hp) {
  const int i = blockIdx.x * blockDim.x + threadIdx.x;
  if (i >= NNODES) return;
  const float il = 1.0f / (sqrtf(deg_lp[i] + 1.0f) + EOS);
  const float ih = 1.0f / (sqrtf(deg_hp[i] + 1.0f) + EOS);
  inv_lp[i] = il;
  inv_hp[i] = ih;
  const size_t diag = (size_t)i * NNODES + i;
  adj_lp[diag] = il * il;
  adj_hp[diag] = 1.0f;
}

// ---------------------------------------------------------------------------
// Pass D: winner edges write normalized adjacency cells + unnorm=1.0.
// Race note: only the winner writes unnorm[cell]=1.0f; non-winner dup
// threads read either the winner id (!= their e+1) or 1.0f bits
// (1065353216 > 192000) — both correctly skip.
// ---------------------------------------------------------------------------
__global__ __launch_bounds__(256) void edge_write_kernel(
    const int* __restrict__ edges, const float* __restrict__ w_lp,
    const float* __restrict__ w_hp, const float* __restrict__ inv_lp,
    const float* __restrict__ inv_hp, float* __restrict__ adj_lp,
    float* __restrict__ adj_hp, float* __restrict__ unnorm) {
  const int e = blockIdx.x * blockDim.x + threadIdx.x;
  if (e >= NEDGES) return;
  const int u = edges[e];
  const int v = edges[NEDGES + e];
  const size_t cell = (size_t)u * NNODES + v;
  const int win = ((const int*)unnorm)[cell];
  if (win != e + 1) return;
  const float wl = w_lp[e];
  const float wh = w_hp[e];
  const float il = inv_lp[u] * inv_lp[v];
  const float ih = inv_hp[u] * inv_hp[v];
  if (u == v) {
    adj_lp[cell] = (wl + 1.0f) * il;
    adj_hp[cell] = 1.0f - (wh + 1.0f) * ih * ALPHA;
  } else {
    adj_lp[cell] = wl * il;
    adj_hp[cell] = -wh * ih * ALPHA;
  }
  unnorm[cell] = 1.0f;
}

extern "C" void kernel_launch(void* const* d_in, const int* in_sizes, int n_in,
                              void* d_out, int out_size, void* d_ws,
                              size_t ws_size, hipStream_t stream) {
  const float* feat  = (const float*)d_in[0];
  const int*   edges = (const int*)d_in[1];
  const float* w_emb = (const float*)d_in[2];
  const float* b_emb = (const float*)d_in[3];
  const float* w_mlp = (const float*)d_in[4];
  const float* b_mlp = (const float*)d_in[5];
  const float* noise = (const float*)d_in[6];

  float* out    = (float*)d_out;
  float* adj_lp = out;                 // [N,N]
  float* adj_hp = out + NN;            // [N,N]
  float* w_lp   = out + 2 * NN;        // [E]
  float* w_hp   = w_lp + NEDGES;       // [E]
  float* unnorm = w_hp + NEDGES;       // [N,N]  (doubles as winner array)

  float* deg_lp = (float*)d_ws;        // [N]
  float* deg_hp = deg_lp + NNODES;     // [N]
  float* inv_lp = deg_hp + NNODES;     // [N]
  float* inv_hp = inv_lp + NNODES;     // [N]
  float* g      = inv_hp + NNODES;     // [N]

  // Zero the three N×N matrices (adj_lp & adj_hp are contiguous) + degrees.
  hipMemsetAsync(adj_lp, 0, 2 * NN * sizeof(float), stream);
  hipMemsetAsync(unnorm, 0, NN * sizeof(float), stream);
  hipMemsetAsync(deg_lp, 0, 2 * NNODES * sizeof(float), stream);

  embed_g_kernel<<<NNODES / 8, 128, 0, stream>>>(feat, w_emb, b_emb, w_mlp, g);

  const int eb = (NEDGES + 255) / 256;
  edge_weights_kernel<<<eb, 256, 0, stream>>>(edges, g, noise, b_mlp, w_lp,
                                              w_hp, (int*)unnorm);
  edge_deg_kernel<<<eb, 256, 0, stream>>>(edges, w_lp, w_hp,
                                          (const int*)unnorm, deg_lp, deg_hp);
  node_inv_kernel<<<(NNODES + 255) / 256, 256, 0, stream>>>(
      deg_lp, deg_hp, inv_lp, inv_hp, adj_lp, adj_hp);
  edge_write_kernel<<<eb, 256, 0, stream>>>(edges, w_lp, w_hp, inv_lp, inv_hp,
                                            adj_lp, adj_hp, unnorm);
}